// Round 14
// baseline (359.395 us; speedup 1.0000x reference)
//
#include <hip/hip_runtime.h>

typedef float floatx16 __attribute__((ext_vector_type(16)));
typedef __bf16 bf16x8 __attribute__((ext_vector_type(8)));
using u16 = unsigned short;
using u32 = unsigned int;

#define GLOBAL_AS __attribute__((address_space(1)))
#define LDS_AS    __attribute__((address_space(3)))

__device__ __forceinline__ u32 rne_bf16(float f) {
  u32 u = __float_as_uint(f);
  return (u + 0x7FFFu + ((u >> 16) & 1u)) >> 16;  // RNE
}

// ---------------- A: fp32 -> bf16, tile-permuted for 32x32x16 frags (R10) ----------------
__global__ __launch_bounds__(256) void cvt_x_perm(const float* __restrict__ x,
                                                  u16* __restrict__ xb, int K) {
  __shared__ u16 sm[16384];
  const int tid = threadIdx.x;
  const int Kt = K >> 6;
  const int pn = blockIdx.x / Kt, tt = blockIdx.x % Kt;
  const float* src = x + (size_t)pn * 256 * K + tt * 64;
#pragma unroll
  for (int j = 0; j < 16; ++j) {
    const int fc = j * 256 + tid;
    const int row = fc >> 4, kl4 = fc & 15;
    const float4 v = *(const float4*)(src + (size_t)row * K + kl4 * 4);
    uint2 o;
    o.x = rne_bf16(v.x) | (rne_bf16(v.y) << 16);
    o.y = rne_bf16(v.z) | (rne_bf16(v.w) << 16);
    const int gi = row >> 5, rowin = row & 31;
    const int ks = kl4 >> 2;
    const int lane = rowin + 32 * ((kl4 >> 1) & 1);
    const int e4 = (kl4 & 1) * 4;
    *(uint2*)(sm + gi * 2048 + ks * 512 + lane * 8 + e4) = o;
  }
  __syncthreads();
  u16* dst = xb + (size_t)pn * 256 * K + (size_t)tt * 16384;
#pragma unroll
  for (int j = 0; j < 8; ++j) {
    const int o = (j * 256 + tid) * 8;
    *(uint4*)(dst + o) = *(const uint4*)(sm + o);
  }
}

// ------- B: fp32 -> 2-bit ternary codes (c=1:+1, c=3:-1, c=0:0), frag-ordered -------
// dst u16 idx = ((bnp*Kt + t)*4 + wc)*512 + l*8 + f, bits[2j+1:2j] = code, where
// n = bnp*256 + wc*64 + (f>>2)*32 + (l&31); k = t*64 + (f&3)*16 + (l>>5)*8 + j.
__global__ void quant_w_pack(const float* __restrict__ w, u16* __restrict__ wb,
                             int K, int Kd8, int n8) {
  int stride = gridDim.x * blockDim.x;
  const int Kt = K >> 6;
  for (int i = blockIdx.x * blockDim.x + threadIdx.x; i < n8; i += stride) {
    const int n = i / Kd8;
    const int k = (i - n * Kd8) * 8;
    const float4* p = (const float4*)(w + (size_t)n * K + k);
    float4 a = p[0], b = p[1];
    float v[8] = {a.x, a.y, a.z, a.w, b.x, b.y, b.z, b.w};
    u32 pk = 0;
#pragma unroll
    for (int j = 0; j < 8; ++j) {
      u32 c = (v[j] > 0.05f) ? 1u : ((v[j] < -0.05f) ? 3u : 0u);
      pk |= c << (2 * j);
    }
    const int bnp = n >> 8, wc = (n >> 6) & 3, ng = (n >> 5) & 1, cc = n & 31;
    const int t = k >> 6, ks = (k >> 4) & 3, h = (k >> 3) & 1;
    const int f = ng * 4 + ks, l = cc + 32 * h;
    wb[(size_t)((bnp * Kt + t) * 4 + wc) * 512 + l * 8 + f] = (u16)pk;
  }
}

// decode one packed u16 (8 codes) -> bf16x8 {0,+1,-1}
__device__ __forceinline__ bf16x8 dec_frag(u32 pkv) {
  union { u32 w[4]; bf16x8 v; } u;
#pragma unroll
  for (int ii = 0; ii < 4; ++ii) {
    u32 x = (pkv >> (4 * ii)) & 0xFu;
    u32 lo = (x & 1u) * 0x3F80u | ((x & 2u) << 14);
    u32 hi = ((x >> 2) & 1u) * 0x3F80u | ((x & 8u) << 12);
    u.w[ii] = lo | (hi << 16);
  }
  return u.v;
}

// ---------------- 256x256 BK=64 GEMM: A in LDS (32KB dbuf), B in regs (2-bit) ----------------
// R13 structure; BUGFIX: pk ping-pong is SELF-replacing (tile t consumes pk(t)
// from reg X in P1/mid, then P3 loads pk(t+2) into the SAME reg X) -- the
// previous cross-rotation clobbered pk(t+1) before tile t+1 used it.
// VMEM FIFO (pk loads count in vmcnt): prologue issues {pk0, A0 x4, A02(1) x2,
// pk1}; vmcnt(3) drains {pk0, A0 x4}. Steady state end-of-tile vmcnt(3) leaves
// exactly {A02(t+2) x2, pk(t+2)}. 2 barriers/tile (B1: WAR for A02->bufc;
// B2: publish bufo/retire bufc).
__global__ __launch_bounds__(512, 2) void gemm_bin_breg(
    const u16* __restrict__ Ap, const u16* __restrict__ Bp,
    const float* __restrict__ bias, float* __restrict__ C,
    int M, int N, int K) {
  __shared__ u16 lds[32768];  // 2 buf x 16384 u16 (A only) = 64 KiB

  const int tid = threadIdx.x;
  const int w = tid >> 6, l = tid & 63;
  const int wr = w >> 2, wc = w & 3;

  const int nbn = N >> 8;
  int wg = blockIdx.x;
  const int nwg = gridDim.x;
  if ((nwg & 7) == 0) wg = (wg & 7) * (nwg >> 3) + (wg >> 3);  // XCD swizzle (bijective)
  const int bm = wg / nbn, bn = wg % nbn;

  const int T = K >> 6;
  const int Kt = T;

  const u16* const Abase = Ap + (size_t)bm * ((size_t)K << 8) + tid * 8;
  const u16* const pkp = Bp + (size_t)((size_t)bn * Kt * 4 + wc) * 512 + l * 8;

  const u16* const afp0 = lds + wr * 8192 + l * 8;

  floatx16 acc[4][2] = {};
  bf16x8 af[8], bflo[4], bfhi[4];
  uint4 pkA, pkB;

#define GLOAD(gptr, u16off)                                                    \
  __builtin_amdgcn_global_load_lds((const GLOBAL_AS void*)(gptr),              \
                                   (LDS_AS void*)(lds + (u16off)), 16, 0, 0)

  // prologue: pk(0); A(0) c0..c3 -> buf0; A02(1) -> buf1; pk(1); vmcnt(3); barrier
  pkA = *(const uint4*)(pkp);
  GLOAD(Abase + 0 * 4096,      0 + tid * 8);
  GLOAD(Abase + 1 * 4096,   4096 + tid * 8);
  GLOAD(Abase + 2 * 4096,   8192 + tid * 8);
  GLOAD(Abase + 3 * 4096,  12288 + tid * 8);
  if (T > 1) {
    GLOAD(Abase + 16384 + 0 * 4096, 16384 + 0 + tid * 8);
    GLOAD(Abase + 16384 + 2 * 4096, 16384 + 8192 + tid * 8);
    pkB = *(const uint4*)(pkp + 2048);
  }
  asm volatile("s_waitcnt vmcnt(3)" ::: "memory");  // A(0)+pk(0) fully landed
  __builtin_amdgcn_s_barrier();

#define TILE(t, PKX)                                                           \
  {                                                                            \
    const int bufc = ((t) & 1) << 14;                                          \
    const int bufo = bufc ^ 16384;                                             \
    const bool st1 = (t) + 1 < T;                                              \
    const bool st2 = (t) + 2 < T;                                              \
    const u16* afp = afp0 + bufc;                                              \
    /* P1: af01 reads + A13(t+1) stage + decode bflo from PKX = pk(t) */       \
    _Pragma("unroll")                                                          \
    for (int m = 0; m < 2; ++m)                                                \
      _Pragma("unroll")                                                        \
      for (int ks = 0; ks < 4; ++ks)                                           \
        af[m * 4 + ks] = *(const bf16x8*)(afp + m * 2048 + ks * 512);          \
    if (st1) {                                                                 \
      const size_t tb_ = (size_t)((t) + 1) * 16384;                            \
      GLOAD(Abase + tb_ + 1 * 4096, bufo + 4096 + tid * 8);                    \
      GLOAD(Abase + tb_ + 3 * 4096, bufo + 12288 + tid * 8);                   \
    }                                                                          \
    _Pragma("unroll")                                                          \
    for (int ks = 0; ks < 4; ++ks) bflo[ks] = dec_frag((ks & 1) ? (((const u32*)&PKX)[ks >> 1] >> 16) : (((const u32*)&PKX)[ks >> 1] & 0xFFFFu)); \
    asm volatile("s_waitcnt lgkmcnt(0)" ::: "memory");                         \
    __builtin_amdgcn_sched_barrier(0);                                         \
    __builtin_amdgcn_s_barrier();  /* B1: all waves' c0/c2 reads done */       \
    __builtin_amdgcn_s_setprio(1);                                             \
    _Pragma("unroll")                                                          \
    for (int ks = 0; ks < 4; ++ks)                                             \
      _Pragma("unroll")                                                        \
      for (int m = 0; m < 2; ++m)                                              \
        acc[m][0] = __builtin_amdgcn_mfma_f32_32x32x16_bf16(                   \
            af[m * 4 + ks], bflo[ks], acc[m][0], 0, 0, 0);                     \
    __builtin_amdgcn_s_setprio(0);                                             \
    /* mid: A02(t+2) stage (post-B1) + decode bfhi + Q1 */                     \
    if (st2) {                                                                 \
      const size_t tb_ = (size_t)((t) + 2) * 16384;                            \
      GLOAD(Abase + tb_ + 0 * 4096, bufc + 0 + tid * 8);                       \
      GLOAD(Abase + tb_ + 2 * 4096, bufc + 8192 + tid * 8);                    \
    }                                                                          \
    _Pragma("unroll")                                                          \
    for (int ks = 0; ks < 4; ++ks) bfhi[ks] = dec_frag((ks & 1) ? (((const u32*)&PKX)[2 + (ks >> 1)] >> 16) : (((const u32*)&PKX)[2 + (ks >> 1)] & 0xFFFFu)); \
    __builtin_amdgcn_s_setprio(1);                                             \
    _Pragma("unroll")                                                          \
    for (int ks = 0; ks < 4; ++ks)                                             \
      _Pragma("unroll")                                                        \
      for (int m = 0; m < 2; ++m)                                              \
        acc[m][1] = __builtin_amdgcn_mfma_f32_32x32x16_bf16(                   \
            af[m * 4 + ks], bfhi[ks], acc[m][1], 0, 0, 0);                     \
    __builtin_amdgcn_s_setprio(0);                                             \
    /* P3: af23 reads (reuse af) + pk(t+2) -> PKX (self-replace; pk(t) fully   \
       consumed above); Q2; Q3 */                                              \
    _Pragma("unroll")                                                          \
    for (int m = 0; m < 2; ++m)                                                \
      _Pragma("unroll")                                                        \
      for (int ks = 0; ks < 4; ++ks)                                           \
        af[m * 4 + ks] = *(const bf16x8*)(afp + 4096 + m * 2048 + ks * 512);   \
    if (st2) PKX = *(const uint4*)(pkp + (size_t)((t) + 2) * 2048);            \
    asm volatile("s_waitcnt lgkmcnt(0)" ::: "memory");                         \
    __builtin_amdgcn_sched_barrier(0);                                         \
    __builtin_amdgcn_s_setprio(1);                                             \
    _Pragma("unroll")                                                          \
    for (int ks = 0; ks < 4; ++ks)                                             \
      _Pragma("unroll")                                                        \
      for (int m = 0; m < 2; ++m)                                              \
        acc[2 + m][0] = __builtin_amdgcn_mfma_f32_32x32x16_bf16(               \
            af[m * 4 + ks], bflo[ks], acc[2 + m][0], 0, 0, 0);                 \
    _Pragma("unroll")                                                          \
    for (int ks = 0; ks < 4; ++ks)                                             \
      _Pragma("unroll")                                                        \
      for (int m = 0; m < 2; ++m)                                              \
        acc[2 + m][1] = __builtin_amdgcn_mfma_f32_32x32x16_bf16(               \
            af[m * 4 + ks], bfhi[ks], acc[2 + m][1], 0, 0, 0);                 \
    __builtin_amdgcn_s_setprio(0);                                             \
    if (st1) {                                                                 \
      if (st2) asm volatile("s_waitcnt vmcnt(3)" ::: "memory");                \
      else     asm volatile("s_waitcnt vmcnt(0)" ::: "memory");                \
      __builtin_amdgcn_s_barrier();  /* B2: publish bufo, retire bufc */       \
    }                                                                          \
  }

  for (int tt = 0; tt < T; tt += 2) {
    TILE(tt,     pkA)   // consumes pk(t), reloads pk(t+2) into same reg
    TILE(tt + 1, pkB)
  }
#undef TILE
#undef GLOAD

  // ---- epilogue: C/D col=l&31, row=(q&3)+8*(q>>2)+4*(l>>5) (m74/m101-verified) ----
  const int colq = l & 31;
  const int hi4 = (l >> 5) * 4;
#pragma unroll
  for (int m = 0; m < 4; ++m) {
    const int rowb = bm * 256 + wr * 128 + m * 32 + hi4;
#pragma unroll
    for (int n = 0; n < 2; ++n) {
      const int col = bn * 256 + wc * 64 + n * 32 + colq;
      const float bv = bias[col];
      float* cp = C + (size_t)rowb * N + col;
#pragma unroll
      for (int q = 0; q < 16; ++q) {
        const int dr = (q & 3) + 8 * (q >> 2);
        cp[(size_t)dr * N] = acc[m][n][q] + bv;
      }
    }
  }
}

// ---------------- fallback: slow but correct ----------------
__global__ void gemm_naive_kernel(const float* __restrict__ x, const float* __restrict__ wgt,
                                  const float* __restrict__ bias, float* __restrict__ out,
                                  int M, int N, int K) {
  long long idx = (long long)blockIdx.x * blockDim.x + threadIdx.x;
  if (idx >= (long long)M * N) return;
  int o = (int)(idx % N);
  int m = (int)(idx / N);
  const float* xr = x + (size_t)m * K;
  const float* wr = wgt + (size_t)o * K;
  float s = 0.f;
  for (int i = 0; i < K; ++i) {
    float wv = wr[i];
    float t = (wv > 0.05f) ? 1.f : ((wv < -0.05f) ? -1.f : 0.f);
    s = fmaf(xr[i], t, s);
  }
  out[idx] = s + bias[o];
}

extern "C" void kernel_launch(void* const* d_in, const int* in_sizes, int n_in,
                              void* d_out, int out_size, void* d_ws, size_t ws_size,
                              hipStream_t stream) {
  const float* x    = (const float*)d_in[0];
  const float* wgt  = (const float*)d_in[1];
  const float* bias = (const float*)d_in[2];
  float* out = (float*)d_out;

  const int N = in_sizes[2];                 // out features
  const int K = in_sizes[1] / N;             // in features
  const int M = in_sizes[0] / K;             // batch rows

  const size_t need = (size_t)M * K * 2 + (size_t)N * K / 4;  // bf16 A + 2-bit B
  if (ws_size >= need && (M % 256 == 0) && (N % 256 == 0) && (K % 128 == 0) && K >= 256) {
    u16* xb = (u16*)d_ws;
    u16* wb = xb + (size_t)M * K;
    const int Kt = K / 64;
    cvt_x_perm<<<(M / 256) * Kt, 256, 0, stream>>>(x, xb, K);
    quant_w_pack<<<2048, 256, 0, stream>>>(wgt, wb, K, K / 8, (N * K) / 8);
    const int grid = (M / 256) * (N / 256);
    gemm_bin_breg<<<grid, 512, 0, stream>>>(xb, wb, bias, out, M, N, K);
  } else {
    const long long total = (long long)M * N;
    gemm_naive_kernel<<<(unsigned)((total + 255) / 256), 256, 0, stream>>>(x, wgt, bias, out, M, N, K);
  }
}

// Round 15
// 288.783 us; speedup vs baseline: 1.2445x; 1.2445x over previous
//
#include <hip/hip_runtime.h>

typedef float floatx16 __attribute__((ext_vector_type(16)));
typedef __bf16 bf16x8 __attribute__((ext_vector_type(8)));
using u16 = unsigned short;
using u32 = unsigned int;

#define GLOBAL_AS __attribute__((address_space(1)))
#define LDS_AS    __attribute__((address_space(3)))

__device__ __forceinline__ u32 rne_bf16(float f) {
  u32 u = __float_as_uint(f);
  return (u + 0x7FFFu + ((u >> 16) & 1u)) >> 16;  // RNE
}

// ---------------- A: fp32 -> bf16, tile-permuted for 32x32x16 frags (R10) ----------------
__global__ __launch_bounds__(256) void cvt_x_perm(const float* __restrict__ x,
                                                  u16* __restrict__ xb, int K) {
  __shared__ u16 sm[16384];
  const int tid = threadIdx.x;
  const int Kt = K >> 6;
  const int pn = blockIdx.x / Kt, tt = blockIdx.x % Kt;
  const float* src = x + (size_t)pn * 256 * K + tt * 64;
#pragma unroll
  for (int j = 0; j < 16; ++j) {
    const int fc = j * 256 + tid;
    const int row = fc >> 4, kl4 = fc & 15;
    const float4 v = *(const float4*)(src + (size_t)row * K + kl4 * 4);
    uint2 o;
    o.x = rne_bf16(v.x) | (rne_bf16(v.y) << 16);
    o.y = rne_bf16(v.z) | (rne_bf16(v.w) << 16);
    const int gi = row >> 5, rowin = row & 31;
    const int ks = kl4 >> 2;
    const int lane = rowin + 32 * ((kl4 >> 1) & 1);
    const int e4 = (kl4 & 1) * 4;
    *(uint2*)(sm + gi * 2048 + ks * 512 + lane * 8 + e4) = o;
  }
  __syncthreads();
  u16* dst = xb + (size_t)pn * 256 * K + (size_t)tt * 16384;
#pragma unroll
  for (int j = 0; j < 8; ++j) {
    const int o = (j * 256 + tid) * 8;
    *(uint4*)(dst + o) = *(const uint4*)(sm + o);
  }
}

// ---------------- B: fp32 -> ternary bf16, same tile-permuted layout ----------------
__global__ __launch_bounds__(256) void quant_w_perm(const float* __restrict__ w,
                                                    u16* __restrict__ wb, int K) {
  __shared__ u16 sm[16384];
  const int tid = threadIdx.x;
  const int Kt = K >> 6;
  const int pn = blockIdx.x / Kt, tt = blockIdx.x % Kt;
  const float* src = w + (size_t)pn * 256 * K + tt * 64;
#pragma unroll
  for (int j = 0; j < 16; ++j) {
    const int fc = j * 256 + tid;
    const int row = fc >> 4, kl4 = fc & 15;
    const float4 v = *(const float4*)(src + (size_t)row * K + kl4 * 4);
    float vv[4] = {v.x, v.y, v.z, v.w};
    u32 r[4];
#pragma unroll
    for (int e = 0; e < 4; ++e)
      r[e] = (vv[e] > 0.05f) ? 0x3F80u : ((vv[e] < -0.05f) ? 0xBF80u : 0u);
    uint2 o;
    o.x = r[0] | (r[1] << 16);
    o.y = r[2] | (r[3] << 16);
    const int gi = row >> 5, rowin = row & 31;
    const int ks = kl4 >> 2;
    const int lane = rowin + 32 * ((kl4 >> 1) & 1);
    const int e4 = (kl4 & 1) * 4;
    *(uint2*)(sm + gi * 2048 + ks * 512 + lane * 8 + e4) = o;
  }
  __syncthreads();
  u16* dst = wb + (size_t)pn * 256 * K + (size_t)tt * 16384;
#pragma unroll
  for (int j = 0; j < 8; ++j) {
    const int o = (j * 256 + tid) * 8;
    *(uint4*)(dst + o) = *(const uint4*)(sm + o);
  }
}

// ---------------- 256x256 BK=64 GEMM, mfma 32x32x16, compiler-scheduled tiles ----------------
// R12 skeleton (8 stage-gloads at tile top -> NEXT buffer only; no in-tile WAR;
// ONE barrier/tile) but with ALL manual lgkm walls / sched_barriers / setprio
// REMOVED inside the tile: fragment reads are compiler-visible C++ loads, so
// hipcc emits fine-grained counted lgkmcnt between ds_read and MFMA -- later
// reads (af23, bfhi) drain UNDER earlier MFMA quadrants (in-wave overlap the
// previous lgkm(0)+sched_barrier(0) walls forbade).
// Tile end: single fused asm {vmcnt(0) lgkmcnt(0); s_barrier} with "memory"
// clobber -- staged tile t+1 published, bufc reads retired, and next tile's
// ds_reads cannot hoist above the barrier.
__global__ __launch_bounds__(512, 2) void gemm_bin_csched(
    const u16* __restrict__ Ap, const u16* __restrict__ Bp,
    const float* __restrict__ bias, float* __restrict__ C,
    int M, int N, int K) {
  __shared__ u16 lds[65536];  // 2 buf x (A 16384 | B 16384) u16

  const int tid = threadIdx.x;
  const int w = tid >> 6, l = tid & 63;
  const int wr = w >> 2, wc = w & 3;

  const int nbn = N >> 8;
  int wg = blockIdx.x;
  const int nwg = gridDim.x;
  if ((nwg & 7) == 0) wg = (wg & 7) * (nwg >> 3) + (wg >> 3);  // XCD swizzle (bijective)
  const int bm = wg / nbn, bn = wg % nbn;

  const int T = K >> 6;

  const u16* const Abase = Ap + (size_t)bm * ((size_t)K << 8) + tid * 8;
  const u16* const Bbase = Bp + (size_t)bn * ((size_t)K << 8) + tid * 8;

  const u16* const afp0 = lds + wr * 8192 + l * 8;            // + m*2048 + ks*512
  const u16* const bfp0 = lds + 16384 + wc * 4096 + l * 8;    // + n*2048 + ks*512

  floatx16 acc[4][2] = {};
  bf16x8 af[8], af2[8], bflo[4], bfhi[4];

#define GLOAD(gptr, u16off)                                                    \
  __builtin_amdgcn_global_load_lds((const GLOBAL_AS void*)(gptr),              \
                                   (LDS_AS void*)(lds + (u16off)), 16, 0, 0)
#define STAGE8(tt, bufdst)                                                     \
  {                                                                            \
    const size_t tb_ = (size_t)(tt) * 16384;                                   \
    GLOAD(Abase + tb_ + 0 * 4096, (bufdst) + 0 + tid * 8);                     \
    GLOAD(Abase + tb_ + 1 * 4096, (bufdst) + 4096 + tid * 8);                  \
    GLOAD(Abase + tb_ + 2 * 4096, (bufdst) + 8192 + tid * 8);                  \
    GLOAD(Abase + tb_ + 3 * 4096, (bufdst) + 12288 + tid * 8);                 \
    GLOAD(Bbase + tb_ + 0 * 4096, (bufdst) + 16384 + tid * 8);                 \
    GLOAD(Bbase + tb_ + 1 * 4096, (bufdst) + 20480 + tid * 8);                 \
    GLOAD(Bbase + tb_ + 2 * 4096, (bufdst) + 24576 + tid * 8);                 \
    GLOAD(Bbase + tb_ + 3 * 4096, (bufdst) + 28672 + tid * 8);                 \
  }
// fused drain + barrier: memory clobber fences load motion across the barrier
#define SYNC_TILE asm volatile("s_waitcnt vmcnt(0) lgkmcnt(0)\ns_barrier" ::: "memory")

  // prologue: stage tile 0 -> buf0, drain, publish
  STAGE8(0, 0)
  SYNC_TILE;

  for (int t = 0; t < T; ++t) {
    const int bufc = (t & 1) << 15;
    const int bufo = bufc ^ 32768;
    const bool st1 = (t + 1 < T);

    if (st1) STAGE8(t + 1, bufo)

    const u16* afp = afp0 + bufc;
    const u16* bfp = bfp0 + bufc;

    // all fragment reads, in consumption order (compiler inserts counted lgkm)
#pragma unroll
    for (int m = 0; m < 2; ++m)
#pragma unroll
      for (int ks = 0; ks < 4; ++ks)
        af[m * 4 + ks] = *(const bf16x8*)(afp + m * 2048 + ks * 512);
#pragma unroll
    for (int ks = 0; ks < 4; ++ks) bflo[ks] = *(const bf16x8*)(bfp + ks * 512);
#pragma unroll
    for (int ks = 0; ks < 4; ++ks) bfhi[ks] = *(const bf16x8*)(bfp + 2048 + ks * 512);
#pragma unroll
    for (int m = 0; m < 2; ++m)
#pragma unroll
      for (int ks = 0; ks < 4; ++ks)
        af2[m * 4 + ks] = *(const bf16x8*)(afp + 4096 + m * 2048 + ks * 512);

    // 4 quadrants; later reads drain under earlier quadrants' MFMAs
#pragma unroll
    for (int ks = 0; ks < 4; ++ks)
#pragma unroll
      for (int m = 0; m < 2; ++m)
        acc[m][0] = __builtin_amdgcn_mfma_f32_32x32x16_bf16(
            af[m * 4 + ks], bflo[ks], acc[m][0], 0, 0, 0);
#pragma unroll
    for (int ks = 0; ks < 4; ++ks)
#pragma unroll
      for (int m = 0; m < 2; ++m)
        acc[m][1] = __builtin_amdgcn_mfma_f32_32x32x16_bf16(
            af[m * 4 + ks], bfhi[ks], acc[m][1], 0, 0, 0);
#pragma unroll
    for (int ks = 0; ks < 4; ++ks)
#pragma unroll
      for (int m = 0; m < 2; ++m)
        acc[2 + m][0] = __builtin_amdgcn_mfma_f32_32x32x16_bf16(
            af2[m * 4 + ks], bflo[ks], acc[2 + m][0], 0, 0, 0);
#pragma unroll
    for (int ks = 0; ks < 4; ++ks)
#pragma unroll
      for (int m = 0; m < 2; ++m)
        acc[2 + m][1] = __builtin_amdgcn_mfma_f32_32x32x16_bf16(
            af2[m * 4 + ks], bfhi[ks], acc[2 + m][1], 0, 0, 0);

    if (st1) SYNC_TILE;
  }
#undef STAGE8
#undef GLOAD
#undef SYNC_TILE

  // ---- epilogue: C/D col=l&31, row=(q&3)+8*(q>>2)+4*(l>>5) (m74/m101-verified) ----
  const int colq = l & 31;
  const int hi4 = (l >> 5) * 4;
#pragma unroll
  for (int m = 0; m < 4; ++m) {
    const int rowb = bm * 256 + wr * 128 + m * 32 + hi4;
#pragma unroll
    for (int n = 0; n < 2; ++n) {
      const int col = bn * 256 + wc * 64 + n * 32 + colq;
      const float bv = bias[col];
      float* cp = C + (size_t)rowb * N + col;
#pragma unroll
      for (int q = 0; q < 16; ++q) {
        const int dr = (q & 3) + 8 * (q >> 2);
        cp[(size_t)dr * N] = acc[m][n][q] + bv;
      }
    }
  }
}

// ---------------- fallback: slow but correct ----------------
__global__ void gemm_naive_kernel(const float* __restrict__ x, const float* __restrict__ wgt,
                                  const float* __restrict__ bias, float* __restrict__ out,
                                  int M, int N, int K) {
  long long idx = (long long)blockIdx.x * blockDim.x + threadIdx.x;
  if (idx >= (long long)M * N) return;
  int o = (int)(idx % N);
  int m = (int)(idx / N);
  const float* xr = x + (size_t)m * K;
  const float* wr = wgt + (size_t)o * K;
  float s = 0.f;
  for (int i = 0; i < K; ++i) {
    float wv = wr[i];
    float t = (wv > 0.05f) ? 1.f : ((wv < -0.05f) ? -1.f : 0.f);
    s = fmaf(xr[i], t, s);
  }
  out[idx] = s + bias[o];
}

extern "C" void kernel_launch(void* const* d_in, const int* in_sizes, int n_in,
                              void* d_out, int out_size, void* d_ws, size_t ws_size,
                              hipStream_t stream) {
  const float* x    = (const float*)d_in[0];
  const float* wgt  = (const float*)d_in[1];
  const float* bias = (const float*)d_in[2];
  float* out = (float*)d_out;

  const int N = in_sizes[2];                 // out features
  const int K = in_sizes[1] / N;             // in features
  const int M = in_sizes[0] / K;             // batch rows

  const size_t need = ((size_t)M * K + (size_t)N * K) * sizeof(u16);
  if (ws_size >= need && (M % 256 == 0) && (N % 256 == 0) && (K % 64 == 0) && K >= 192) {
    u16* xb = (u16*)d_ws;
    u16* wb = xb + (size_t)M * K;
    const int Kt = K / 64;
    cvt_x_perm<<<(M / 256) * Kt, 256, 0, stream>>>(x, xb, K);
    quant_w_perm<<<(N / 256) * Kt, 256, 0, stream>>>(wgt, wb, K);
    const int grid = (M / 256) * (N / 256);
    gemm_bin_csched<<<grid, 512, 0, stream>>>(xb, wb, bias, out, M, N, K);
  } else {
    const long long total = (long long)M * N;
    gemm_naive_kernel<<<(unsigned)((total + 255) / 256), 256, 0, stream>>>(x, wgt, bias, out, M, N, K);
  }
}